// Round 2
// baseline (1015.403 us; speedup 1.0000x reference)
//
#include <hip/hip_runtime.h>
#include <hip/hip_bf16.h>

typedef float f32x4 __attribute__((ext_vector_type(4)));

#define N_NODES 100000
#define HID 32

// ---------------- edge dtype detect: mode=1 -> int32 layout, mode=0 -> int64 (low/high words) ----
__global__ void k_detect(const int* __restrict__ ei, int* __restrict__ mode) {
    __shared__ int flag;
    if (threadIdx.x == 0) flag = 0;
    __syncthreads();
    int f = 0;
    for (int i = threadIdx.x; i < 4096; i += 256)
        if (ei[2 * i + 1] != 0) f = 1;
    if (f) flag = 1;   // benign race: all writers store 1
    __syncthreads();
    if (threadIdx.x == 0) *mode = flag;
}

// ---------------- zero an int array ----------------
__global__ void k_zero(int* p, int n) {
    int i = blockIdx.x * 256 + threadIdx.x;
    if (i < n) p[i] = 0;
}

// ---------------- degree histogram over dst ----------------
__global__ void k_hist(const int* __restrict__ ei, const int* __restrict__ mode,
                       int* __restrict__ cnt, int E) {
    int e = blockIdx.x * 256 + threadIdx.x;
    if (e >= E) return;
    int m = *mode;
    int d = m ? ei[E + e] : ei[2 * (E + e)];
    if ((unsigned)d < N_NODES) atomicAdd(&cnt[d], 1);
}

// ---------------- scan phase A: per-block sums ----------------
__global__ void k_bsum(const int* __restrict__ cnt, int* __restrict__ bsum, int n) {
    __shared__ int s[256];
    int tid = threadIdx.x;
    int i = blockIdx.x * 256 + tid;
    s[tid] = (i < n) ? cnt[i] : 0;
    __syncthreads();
    for (int d = 128; d > 0; d >>= 1) {
        if (tid < d) s[tid] += s[tid + d];
        __syncthreads();
    }
    if (tid == 0) bsum[blockIdx.x] = s[0];
}

// ---------------- scan phase B: scan of block sums (1 block, 512 thr) ----------------
__global__ void k_scan_top(const int* __restrict__ bsum, int* __restrict__ boff, int nb) {
    __shared__ int s[512];
    int tid = threadIdx.x;
    int v = (tid < nb) ? bsum[tid] : 0;
    s[tid] = v;
    __syncthreads();
    for (int d = 1; d < 512; d <<= 1) {
        int t = (tid >= d) ? s[tid - d] : 0;
        __syncthreads();
        s[tid] += t;
        __syncthreads();
    }
    if (tid < nb) boff[tid] = s[tid] - v;   // exclusive
}

// ---------------- scan phase C: rowptr + dinv + zero fill ----------------
__global__ void k_scan_bot(const int* __restrict__ cnt, const int* __restrict__ boff,
                           int* __restrict__ rowptr, float* __restrict__ dinv,
                           int* __restrict__ fill, int n) {
    __shared__ int s[256];
    int tid = threadIdx.x;
    int i = blockIdx.x * 256 + tid;
    int v = (i < n) ? cnt[i] : 0;
    s[tid] = v;
    __syncthreads();
    for (int d = 1; d < 256; d <<= 1) {
        int t = (tid >= d) ? s[tid - d] : 0;
        __syncthreads();
        s[tid] += t;
        __syncthreads();
    }
    int incl = s[tid];
    if (i < n) {
        rowptr[i] = boff[blockIdx.x] + incl - v;
        if (i == n - 1) rowptr[n] = boff[blockIdx.x] + incl;
        dinv[i] = rsqrtf((float)v + 1.0f);
        fill[i] = 0;
    }
}

// ---------------- CSR scatter ----------------
__global__ void k_scatter(const int* __restrict__ ei, const int* __restrict__ mode,
                          const int* __restrict__ rowptr, int* __restrict__ fill,
                          int* __restrict__ csr, int E) {
    int e = blockIdx.x * 256 + threadIdx.x;
    if (e >= E) return;
    int m = *mode;
    int s = m ? ei[e] : ei[2 * e];
    int d = m ? ei[E + e] : ei[2 * (E + e)];
    if ((unsigned)s >= N_NODES) s = 0;
    if ((unsigned)d < N_NODES) {
        int pos = rowptr[d] + atomicAdd(&fill[d], 1);
        csr[pos] = s;
    }
}

// ---------------- GEMM1: H[100000,32] = X[100000,512] @ W[512,32], all f32 ----------------
// One row per thread; x tile + W chunk staged in LDS.
__global__ __launch_bounds__(256) void k_gemm1(const float* __restrict__ X,
                                               const float* __restrict__ W,
                                               float* __restrict__ H) {
    __shared__ float xs[256 * 33];   // 256 rows x 32 k, pad 33 (bank-conflict-free)
    __shared__ float ws[32 * 32];    // W chunk [kk][c]
    int tid = threadIdx.x;
    int row0 = blockIdx.x * 256;
    float acc[32];
#pragma unroll
    for (int c = 0; c < 32; c++) acc[c] = 0.f;

    for (int k0 = 0; k0 < 512; k0 += 32) {
        __syncthreads();   // protect previous iter's LDS reads
#pragma unroll
        for (int u = 0; u < 4; u++) {
            int t = u * 256 + tid;
            ws[t] = W[(k0 + (t >> 5)) * 32 + (t & 31)];
        }
#pragma unroll
        for (int u = 0; u < 8; u++) {
            int t = u * 256 + tid;
            int rr = t >> 3, j = t & 7;     // row-in-block, float4-in-row
            long grow = (long)row0 + rr;
            f32x4 v = {0.f, 0.f, 0.f, 0.f};
            if (grow < N_NODES) v = *(const f32x4*)&X[grow * 512 + k0 + 4 * j];
            float* dp = &xs[rr * 33 + 4 * j];
            dp[0] = v.x; dp[1] = v.y; dp[2] = v.z; dp[3] = v.w;
        }
        __syncthreads();
#pragma unroll
        for (int kk = 0; kk < 32; kk++) {
            float xk = xs[tid * 33 + kk];
#pragma unroll
            for (int c = 0; c < 32; c += 4) {
                f32x4 wv = *(const f32x4*)&ws[kk * 32 + c];
                acc[c]     += xk * wv.x;
                acc[c + 1] += xk * wv.y;
                acc[c + 2] += xk * wv.z;
                acc[c + 3] += xk * wv.w;
            }
        }
    }
    long row = (long)row0 + tid;
    if (row < N_NODES) {
        f32x4* hp = (f32x4*)&H[row * 32];
#pragma unroll
        for (int c = 0; c < 8; c++) {
            f32x4 v;
            v.x = acc[4 * c]; v.y = acc[4 * c + 1];
            v.z = acc[4 * c + 2]; v.w = acc[4 * c + 3];
            hp[c] = v;
        }
    }
}

// ---------------- aggregation: out = relu(dinv[i]*sum_e h[src]*dinv[src] + h[i]*dinv[i]^2 + b) ----
__global__ __launch_bounds__(256) void k_agg(const float* __restrict__ H,
                                             const int* __restrict__ rowptr,
                                             const int* __restrict__ csr,
                                             const float* __restrict__ dinv,
                                             const float* __restrict__ bias,
                                             float* __restrict__ Xout, int n) {
    int tid = threadIdx.x;
    int node = blockIdx.x * 8 + (tid >> 5);
    int f = tid & 31;
    if (node >= n) return;
    int e0 = rowptr[node], e1 = rowptr[node + 1];
    float acc = 0.f;
    int e = e0;
    for (; e + 1 < e1; e += 2) {
        int s0 = csr[e];
        int s1 = csr[e + 1];
        float v0 = H[(long)s0 * 32 + f] * dinv[s0];
        float v1 = H[(long)s1 * 32 + f] * dinv[s1];
        acc += v0 + v1;
    }
    if (e < e1) {
        int s0 = csr[e];
        acc += H[(long)s0 * 32 + f] * dinv[s0];
    }
    float dv = dinv[node];
    float r = acc * dv + H[(long)node * 32 + f] * dv * dv + bias[f];
    Xout[(long)node * 32 + f] = fmaxf(r, 0.f);
}

// ---------------- small GEMM: H[n,32] = X[n,32] @ W[32,32], all f32 ----------------
__global__ __launch_bounds__(256) void k_gemm_s(const float* __restrict__ X,
                                                const float* __restrict__ W,
                                                float* __restrict__ H, int n) {
    __shared__ float wl[1024];
    int tid = threadIdx.x;
    for (int t = tid; t < 1024; t += 256) wl[t] = W[t];
    __syncthreads();
    int r = blockIdx.x * 256 + tid;
    if (r >= n) return;
    float x[32];
    const f32x4* xv = (const f32x4*)(X + (long)r * 32);
#pragma unroll
    for (int i = 0; i < 8; i++) {
        f32x4 v = xv[i];
        x[4 * i] = v.x; x[4 * i + 1] = v.y; x[4 * i + 2] = v.z; x[4 * i + 3] = v.w;
    }
    float acc[32];
#pragma unroll
    for (int c = 0; c < 32; c++) acc[c] = 0.f;
#pragma unroll
    for (int k = 0; k < 32; k++) {
        float xk = x[k];
#pragma unroll
        for (int c = 0; c < 32; c += 4) {
            f32x4 wv = *(const f32x4*)&wl[k * 32 + c];
            acc[c] += xk * wv.x; acc[c + 1] += xk * wv.y;
            acc[c + 2] += xk * wv.z; acc[c + 3] += xk * wv.w;
        }
    }
    f32x4* hv = (f32x4*)(H + (long)r * 32);
#pragma unroll
    for (int c = 0; c < 8; c++) {
        f32x4 v;
        v.x = acc[4 * c]; v.y = acc[4 * c + 1];
        v.z = acc[4 * c + 2]; v.w = acc[4 * c + 3];
        hv[c] = v;
    }
}

// ---------------- head: out = relu(x@lin1+b1)@lin2+b2, f32 out ----------------
__global__ __launch_bounds__(256) void k_head(const float* __restrict__ X,
                                              const float* __restrict__ L1W,
                                              const float* __restrict__ L1B,
                                              const float* __restrict__ L2W,
                                              const float* __restrict__ L2B,
                                              float* __restrict__ out, int n) {
    __shared__ float w1[512];    // [32][16]
    __shared__ float w2[192];    // [16][12] (cols 10,11 zero-pad)
    __shared__ float bb1[16];
    __shared__ float bb2[12];
    int tid = threadIdx.x;
    for (int t = tid; t < 512; t += 256) w1[t] = L1W[t];
    if (tid < 192) {
        int k = tid / 12, c = tid % 12;
        w2[tid] = (c < 10) ? L2W[k * 10 + c] : 0.f;
    }
    if (tid < 16) bb1[tid] = L1B[tid];
    if (tid < 12) bb2[tid] = (tid < 10) ? L2B[tid] : 0.f;
    __syncthreads();
    int r = blockIdx.x * 256 + tid;
    if (r >= n) return;
    float x[32];
    const f32x4* xv = (const f32x4*)(X + (long)r * 32);
#pragma unroll
    for (int i = 0; i < 8; i++) {
        f32x4 v = xv[i];
        x[4 * i] = v.x; x[4 * i + 1] = v.y; x[4 * i + 2] = v.z; x[4 * i + 3] = v.w;
    }
    float t1[16];
#pragma unroll
    for (int c = 0; c < 16; c++) t1[c] = bb1[c];
#pragma unroll
    for (int k = 0; k < 32; k++) {
        float xk = x[k];
#pragma unroll
        for (int c = 0; c < 16; c += 4) {
            f32x4 wv = *(const f32x4*)&w1[k * 16 + c];
            t1[c] += xk * wv.x; t1[c + 1] += xk * wv.y;
            t1[c + 2] += xk * wv.z; t1[c + 3] += xk * wv.w;
        }
    }
#pragma unroll
    for (int c = 0; c < 16; c++) t1[c] = fmaxf(t1[c], 0.f);
    float o[12];
#pragma unroll
    for (int c = 0; c < 12; c++) o[c] = bb2[c];
#pragma unroll
    for (int k = 0; k < 16; k++) {
        float xk = t1[k];
#pragma unroll
        for (int c = 0; c < 12; c += 4) {
            f32x4 wv = *(const f32x4*)&w2[k * 12 + c];
            o[c] += xk * wv.x; o[c + 1] += xk * wv.y;
            o[c + 2] += xk * wv.z; o[c + 3] += xk * wv.w;
        }
    }
    // 10 floats per row; row byte offset r*40 is 8-aligned -> float2 stores
    float2* op = (float2*)(out + (long)r * 10);
#pragma unroll
    for (int c = 0; c < 5; c++) {
        float2 v; v.x = o[2 * c]; v.y = o[2 * c + 1];
        op[c] = v;
    }
}

extern "C" void kernel_launch(void* const* d_in, const int* in_sizes, int n_in,
                              void* d_out, int out_size, void* d_ws, size_t ws_size,
                              hipStream_t stream) {
    const float* x0 = (const float*)d_in[0];
    const int* ei = (const int*)d_in[1];
    const float* W1 = (const float*)d_in[3];
    const float* b1 = (const float*)d_in[4];
    const float* W2 = (const float*)d_in[5];
    const float* b2 = (const float*)d_in[6];
    const float* W3 = (const float*)d_in[7];
    const float* b3 = (const float*)d_in[8];
    const float* l1W = (const float*)d_in[9];
    const float* l1b = (const float*)d_in[10];
    const float* l2W = (const float*)d_in[11];
    const float* l2b = (const float*)d_in[12];

    const int E = in_sizes[1] / 2;
    const int N = N_NODES;

    char* w = (char*)d_ws;
    float* h      = (float*)(w);                   // 12,800,000 B
    float* xb     = (float*)(w + 12800000);        // 12,800,000 B
    int*   cnt    = (int*)  (w + 25600000);        //    400,000 B
    int*   rowptr = (int*)  (w + 26000000);        //    400,016 B
    float* dinv   = (float*)(w + 26400016);        //    400,000 B
    int*   fill   = (int*)  (w + 26800016);        //    400,000 B
    int*   bsum   = (int*)  (w + 27200016);        //      4,000 B
    int*   boff   = (int*)  (w + 27204016);        //      4,000 B
    int*   csr    = (int*)  (w + 27208016);        // 12,800,000 B
    int*   mode   = (int*)  (w + 40008016);        //          4 B

    const int NB = (N + 255) / 256;       // 391
    const int EB = (E + 255) / 256;       // 12500
    const int AGB = (N + 7) / 8;          // 12500

    // --- graph structure (recomputed every call; ws is re-poisoned) ---
    k_detect<<<1, 256, 0, stream>>>(ei, mode);
    k_zero<<<NB, 256, 0, stream>>>(cnt, N);
    k_hist<<<EB, 256, 0, stream>>>(ei, mode, cnt, E);
    k_bsum<<<NB, 256, 0, stream>>>(cnt, bsum, N);
    k_scan_top<<<1, 512, 0, stream>>>(bsum, boff, NB);
    k_scan_bot<<<NB, 256, 0, stream>>>(cnt, boff, rowptr, dinv, fill, N);
    k_scatter<<<EB, 256, 0, stream>>>(ei, mode, rowptr, fill, csr, E);

    // --- layer 1 ---
    k_gemm1<<<NB, 256, 0, stream>>>(x0, W1, h);
    k_agg<<<AGB, 256, 0, stream>>>(h, rowptr, csr, dinv, b1, xb, N);
    // --- layer 2 ---
    k_gemm_s<<<NB, 256, 0, stream>>>(xb, W2, h, N);
    k_agg<<<AGB, 256, 0, stream>>>(h, rowptr, csr, dinv, b2, xb, N);
    // --- layer 3 ---
    k_gemm_s<<<NB, 256, 0, stream>>>(xb, W3, h, N);
    k_agg<<<AGB, 256, 0, stream>>>(h, rowptr, csr, dinv, b3, xb, N);
    // --- head ---
    k_head<<<NB, 256, 0, stream>>>(xb, l1W, l1b, l2W, l2b, (float*)d_out, N);
}

// Round 3
// 924.254 us; speedup vs baseline: 1.0986x; 1.0986x over previous
//
#include <hip/hip_runtime.h>
#include <hip/hip_bf16.h>

typedef float f32x4 __attribute__((ext_vector_type(4)));

#define N_NODES 100000
#define NCHUNK 16

// ---------------- edge dtype detect: mode=1 -> int32 layout, mode=0 -> int64 (low/high words) ----
__global__ void k_detect(const int* __restrict__ ei, int* __restrict__ mode) {
    __shared__ int flag;
    if (threadIdx.x == 0) flag = 0;
    __syncthreads();
    int f = 0;
    for (int i = threadIdx.x; i < 4096; i += 256)
        if (ei[2 * i + 1] != 0) f = 1;
    if (f) flag = 1;   // benign race: all writers store 1
    __syncthreads();
    if (threadIdx.x == 0) *mode = flag;
}

// ---------------- zero an int array ----------------
__global__ void k_zero(int* p, int n) {
    int i = blockIdx.x * 256 + threadIdx.x;
    if (i < n) p[i] = 0;
}

// ---------------- pack edges to int2{src,dst} + degree histogram (fused) ----------------
__global__ void k_pack_hist(const int* __restrict__ ei, const int* __restrict__ mode,
                            int2* __restrict__ pairs, int* __restrict__ cnt, int E) {
    int e = blockIdx.x * 256 + threadIdx.x;
    if (e >= E) return;
    int m = *mode;
    int s = m ? ei[e] : ei[2 * e];
    int d = m ? ei[E + e] : ei[2 * (E + e)];
    if ((unsigned)s >= N_NODES) s = 0;
    if ((unsigned)d >= N_NODES) d = 0;
    int2 p; p.x = s; p.y = d;
    pairs[e] = p;
    atomicAdd(&cnt[d], 1);
}

// ---------------- scan phase A: per-block sums ----------------
__global__ void k_bsum(const int* __restrict__ cnt, int* __restrict__ bsum, int n) {
    __shared__ int s[256];
    int tid = threadIdx.x;
    int i = blockIdx.x * 256 + tid;
    s[tid] = (i < n) ? cnt[i] : 0;
    __syncthreads();
    for (int d = 128; d > 0; d >>= 1) {
        if (tid < d) s[tid] += s[tid + d];
        __syncthreads();
    }
    if (tid == 0) bsum[blockIdx.x] = s[0];
}

// ---------------- scan phase B: scan of block sums (1 block, 512 thr) ----------------
__global__ void k_scan_top(const int* __restrict__ bsum, int* __restrict__ boff, int nb) {
    __shared__ int s[512];
    int tid = threadIdx.x;
    int v = (tid < nb) ? bsum[tid] : 0;
    s[tid] = v;
    __syncthreads();
    for (int d = 1; d < 512; d <<= 1) {
        int t = (tid >= d) ? s[tid - d] : 0;
        __syncthreads();
        s[tid] += t;
        __syncthreads();
    }
    if (tid < nb) boff[tid] = s[tid] - v;   // exclusive
}

// ---------------- scan phase C: rowptr + dinv + zero fill ----------------
__global__ void k_scan_bot(const int* __restrict__ cnt, const int* __restrict__ boff,
                           int* __restrict__ rowptr, float* __restrict__ dinv,
                           int* __restrict__ fill, int n) {
    __shared__ int s[256];
    int tid = threadIdx.x;
    int i = blockIdx.x * 256 + tid;
    int v = (i < n) ? cnt[i] : 0;
    s[tid] = v;
    __syncthreads();
    for (int d = 1; d < 256; d <<= 1) {
        int t = (tid >= d) ? s[tid - d] : 0;
        __syncthreads();
        s[tid] += t;
        __syncthreads();
    }
    int incl = s[tid];
    if (i < n) {
        rowptr[i] = boff[blockIdx.x] + incl - v;
        if (i == n - 1) rowptr[n] = boff[blockIdx.x] + incl;
        dinv[i] = rsqrtf((float)v + 1.0f);
        fill[i] = 0;
    }
}

// ---------------- CSR scatter, dst-range chunked to kill write amplification ----------------
// Each pass only scatters edges whose dst is in a 6250-node window -> csr writes land in a
// ~0.8 MB region that stays cache-resident until lines are full.
__global__ __launch_bounds__(256) void k_scatter(const int4* __restrict__ pairs4,
                                                 const int* __restrict__ rowptr,
                                                 int* __restrict__ fill,
                                                 int* __restrict__ csr, int half) {
    int gtid = blockIdx.x * 256 + threadIdx.x;
    int gstride = gridDim.x * 256;
    const int CH = (N_NODES + NCHUNK - 1) / NCHUNK;   // 6250
    for (int c = 0; c < NCHUNK; c++) {
        int lo = c * CH;
        for (int i = gtid; i < half; i += gstride) {
            int4 p = pairs4[i];    // two edges: (x,y) and (z,w)
            if ((unsigned)(p.y - lo) < (unsigned)CH) {
                int pos = rowptr[p.y] + atomicAdd(&fill[p.y], 1);
                csr[pos] = p.x;
            }
            if ((unsigned)(p.w - lo) < (unsigned)CH) {
                int pos = rowptr[p.w] + atomicAdd(&fill[p.w], 1);
                csr[pos] = p.z;
            }
        }
    }
}

// ---------------- GEMM1: H[100000,32] = X[100000,512] @ W[512,32], f32, split-K x4 ----------------
// Block = 256 thr = 4 waves; 64 rows/block; wave w handles K-chunk w (128 of 512 K).
// LDS union: staging (xs 64x65 + ws 64x32 = 6208 f32) then reduction (4*64*33 = 8448 f32).
__global__ __launch_bounds__(256) void k_gemm1(const float* __restrict__ X,
                                               const float* __restrict__ W,
                                               float* __restrict__ H) {
    __shared__ float lds[8448];
    float* xs  = lds;          // [64][65]
    float* wsw = lds + 4160;   // [64][32]
    int tid = threadIdx.x;
    int row = tid & 63;        // lane
    int kc  = tid >> 6;        // wave
    long row0 = (long)blockIdx.x * 64;

    float acc[32];
#pragma unroll
    for (int c = 0; c < 32; c++) acc[c] = 0.f;

    for (int k0 = 0; k0 < 512; k0 += 64) {
        __syncthreads();
        // W chunk: 64x32 contiguous
#pragma unroll
        for (int u = 0; u < 8; u++) {
            int idx = u * 256 + tid;
            wsw[idx] = W[k0 * 32 + idx];
        }
        // X tile: 64 rows x 64 k
#pragma unroll
        for (int u = 0; u < 4; u++) {
            int idx = u * 256 + tid;
            int rr = idx >> 4, j = idx & 15;
            long grow = row0 + rr;
            f32x4 v = {0.f, 0.f, 0.f, 0.f};
            if (grow < N_NODES) v = *(const f32x4*)&X[grow * 512 + k0 + 4 * j];
            float* dp = &xs[rr * 65 + 4 * j];
            dp[0] = v.x; dp[1] = v.y; dp[2] = v.z; dp[3] = v.w;
        }
        __syncthreads();
        int kbase = kc * 16;
#pragma unroll
        for (int kk = 0; kk < 16; kk++) {
            float xk = xs[row * 65 + kbase + kk];
            const float* wrow = &wsw[(kbase + kk) * 32];
#pragma unroll
            for (int c = 0; c < 32; c += 4) {
                f32x4 wv = *(const f32x4*)&wrow[c];
                acc[c]     += xk * wv.x;
                acc[c + 1] += xk * wv.y;
                acc[c + 2] += xk * wv.z;
                acc[c + 3] += xk * wv.w;
            }
        }
    }
    // cross-wave split-K reduction through LDS
    __syncthreads();
#pragma unroll
    for (int c = 0; c < 32; c++) lds[(kc * 64 + row) * 33 + c] = acc[c];
    __syncthreads();
#pragma unroll
    for (int i = 0; i < 8; i++) {
        int o = i * 256 + tid;
        int r = o >> 5, c = o & 31;
        float s = lds[r * 33 + c] + lds[(64 + r) * 33 + c]
                + lds[(128 + r) * 33 + c] + lds[(192 + r) * 33 + c];
        long grow = row0 + r;
        if (grow < N_NODES) H[grow * 32 + c] = s;
    }
}

// ---------------- fused: x = relu(agg(H)+b); Hout = x @ W(32x32) ----------------
__global__ __launch_bounds__(256) void k_agg_mm(const float* __restrict__ H,
                                                const int* __restrict__ rowptr,
                                                const int* __restrict__ csr,
                                                const float* __restrict__ dinv,
                                                const float* __restrict__ bias,
                                                const float* __restrict__ W,
                                                float* __restrict__ Hout, int n) {
    __shared__ float ws[1024];
    int tid = threadIdx.x;
    for (int t = tid; t < 1024; t += 256) ws[t] = W[t];
    __syncthreads();
    int node = blockIdx.x * 8 + (tid >> 5);
    int f = tid & 31;
    if (node >= n) return;
    int e0 = rowptr[node], e1 = rowptr[node + 1];
    float a0 = 0.f, a1 = 0.f, a2 = 0.f, a3 = 0.f;
    int e = e0;
    for (; e + 3 < e1; e += 4) {
        int s0 = csr[e], s1 = csr[e + 1], s2 = csr[e + 2], s3 = csr[e + 3];
        a0 += H[(long)s0 * 32 + f] * dinv[s0];
        a1 += H[(long)s1 * 32 + f] * dinv[s1];
        a2 += H[(long)s2 * 32 + f] * dinv[s2];
        a3 += H[(long)s3 * 32 + f] * dinv[s3];
    }
    for (; e < e1; e++) {
        int s0 = csr[e];
        a0 += H[(long)s0 * 32 + f] * dinv[s0];
    }
    float dv = dinv[node];
    float v = ((a0 + a1) + (a2 + a3)) * dv + H[(long)node * 32 + f] * dv * dv + bias[f];
    v = fmaxf(v, 0.f);
    // x @ W: lane f computes output col f; x[k] via intra-32 shuffle
    float o = 0.f;
#pragma unroll
    for (int k = 0; k < 32; k++) {
        float vk = __shfl(v, k, 32);
        o += vk * ws[k * 32 + f];
    }
    Hout[(long)node * 32 + f] = o;
}

// ---------------- fused: x3 = relu(agg(H)+b); out = relu(x3@lin1+b1)@lin2+b2 ----------------
__global__ __launch_bounds__(256) void k_agg_head(const float* __restrict__ H,
                                                  const int* __restrict__ rowptr,
                                                  const int* __restrict__ csr,
                                                  const float* __restrict__ dinv,
                                                  const float* __restrict__ bias,
                                                  const float* __restrict__ L1W,
                                                  const float* __restrict__ L1B,
                                                  const float* __restrict__ L2W,
                                                  const float* __restrict__ L2B,
                                                  float* __restrict__ out, int n) {
    __shared__ float w1[512];   // [32][16]
    __shared__ float w2[160];   // [16][10]
    __shared__ float bb1[16];
    __shared__ float bb2[10];
    int tid = threadIdx.x;
    for (int t = tid; t < 512; t += 256) w1[t] = L1W[t];
    if (tid < 160) w2[tid] = L2W[tid];
    if (tid < 16) bb1[tid] = L1B[tid];
    if (tid < 10) bb2[tid] = L2B[tid];
    __syncthreads();
    int node = blockIdx.x * 8 + (tid >> 5);
    int f = tid & 31;
    if (node >= n) return;
    int e0 = rowptr[node], e1 = rowptr[node + 1];
    float a0 = 0.f, a1 = 0.f, a2 = 0.f, a3 = 0.f;
    int e = e0;
    for (; e + 3 < e1; e += 4) {
        int s0 = csr[e], s1 = csr[e + 1], s2 = csr[e + 2], s3 = csr[e + 3];
        a0 += H[(long)s0 * 32 + f] * dinv[s0];
        a1 += H[(long)s1 * 32 + f] * dinv[s1];
        a2 += H[(long)s2 * 32 + f] * dinv[s2];
        a3 += H[(long)s3 * 32 + f] * dinv[s3];
    }
    for (; e < e1; e++) {
        int s0 = csr[e];
        a0 += H[(long)s0 * 32 + f] * dinv[s0];
    }
    float dv = dinv[node];
    float v = ((a0 + a1) + (a2 + a3)) * dv + H[(long)node * 32 + f] * dv * dv + bias[f];
    v = fmaxf(v, 0.f);
    // lin1 (32->16) + relu: lane f<16 computes t1[f] (f>=16 compute garbage, unused)
    int c1 = f & 15;
    float t1 = 0.f;
#pragma unroll
    for (int k = 0; k < 32; k++) {
        float vk = __shfl(v, k, 32);
        t1 += vk * w1[k * 16 + c1];
    }
    t1 = fmaxf(t1 + bb1[c1], 0.f);
    // lin2 (16->10): lane f<10 computes out[f]; shfl pulls t1 from lanes 0..15
    int c2 = (f < 10) ? f : 0;
    float o = 0.f;
#pragma unroll
    for (int k = 0; k < 16; k++) {
        float tk = __shfl(t1, k, 32);
        o += tk * w2[k * 10 + c2];
    }
    o += bb2[c2];
    if (f < 10) out[(long)node * 10 + f] = o;
}

extern "C" void kernel_launch(void* const* d_in, const int* in_sizes, int n_in,
                              void* d_out, int out_size, void* d_ws, size_t ws_size,
                              hipStream_t stream) {
    const float* x0 = (const float*)d_in[0];
    const int* ei = (const int*)d_in[1];
    const float* W1 = (const float*)d_in[3];
    const float* b1 = (const float*)d_in[4];
    const float* W2 = (const float*)d_in[5];
    const float* b2 = (const float*)d_in[6];
    const float* W3 = (const float*)d_in[7];
    const float* b3 = (const float*)d_in[8];
    const float* l1W = (const float*)d_in[9];
    const float* l1b = (const float*)d_in[10];
    const float* l2W = (const float*)d_in[11];
    const float* l2b = (const float*)d_in[12];

    const int E = in_sizes[1] / 2;
    const int N = N_NODES;

    char* w = (char*)d_ws;
    // pairs (25.6 MB) aliases h+xb: pairs dead before k_gemm1 writes h.
    float* h      = (float*)(w);                   // 12,800,000 B
    float* xb     = (float*)(w + 12800000);        // 12,800,000 B
    int2*  pairs  = (int2*) (w);                   // 25,600,000 B (aliases h,xb)
    int*   cnt    = (int*)  (w + 25600000);        //    400,000 B
    int*   rowptr = (int*)  (w + 26000000);        //    400,016 B
    float* dinv   = (float*)(w + 26400016);        //    400,000 B
    int*   fill   = (int*)  (w + 26800016);        //    400,000 B
    int*   bsum   = (int*)  (w + 27200016);        //      4,000 B
    int*   boff   = (int*)  (w + 27204016);        //      4,000 B
    int*   csr    = (int*)  (w + 27208016);        // 12,800,000 B
    int*   mode   = (int*)  (w + 40008016);        //          4 B

    const int NB  = (N + 255) / 256;      // 391
    const int EB  = (E + 255) / 256;      // 12500
    const int AGB = (N + 7) / 8;          // 12500
    const int G1B = (N + 63) / 64;        // 1563

    // --- graph structure (recomputed every call; ws is re-poisoned) ---
    k_detect<<<1, 256, 0, stream>>>(ei, mode);
    k_zero<<<NB, 256, 0, stream>>>(cnt, N);
    k_pack_hist<<<EB, 256, 0, stream>>>(ei, mode, pairs, cnt, E);
    k_bsum<<<NB, 256, 0, stream>>>(cnt, bsum, N);
    k_scan_top<<<1, 512, 0, stream>>>(bsum, boff, NB);
    k_scan_bot<<<NB, 256, 0, stream>>>(cnt, boff, rowptr, dinv, fill, N);
    k_scatter<<<1024, 256, 0, stream>>>((const int4*)pairs, rowptr, fill, csr, E / 2);

    // --- layers (transform + head fused into aggregation epilogues) ---
    k_gemm1<<<G1B, 256, 0, stream>>>(x0, W1, h);
    k_agg_mm<<<AGB, 256, 0, stream>>>(h, rowptr, csr, dinv, b1, W2, xb, N);
    k_agg_mm<<<AGB, 256, 0, stream>>>(xb, rowptr, csr, dinv, b2, W3, h, N);
    k_agg_head<<<AGB, 256, 0, stream>>>(h, rowptr, csr, dinv, b3,
                                        l1W, l1b, l2W, l2b, (float*)d_out, N);
}

// Round 4
// 792.711 us; speedup vs baseline: 1.2809x; 1.1659x over previous
//
#include <hip/hip_runtime.h>
#include <hip/hip_bf16.h>

typedef float f32x4 __attribute__((ext_vector_type(4)));

#define N_NODES 100000
#define NBUK 391          // ceil(100000/256) coarse buckets of 256 nodes
#define BSHIFT 8
#define HBLK 256          // partition blocks for hist/bucketize (must match)

// ---------------- edge dtype detect: mode=1 -> int32 layout, mode=0 -> int64 (low/high words) ----
__global__ void k_detect(const int* __restrict__ ei, int* __restrict__ mode) {
    __shared__ int flag;
    if (threadIdx.x == 0) flag = 0;
    __syncthreads();
    int f = 0;
    for (int i = threadIdx.x; i < 4096; i += 256)
        if (ei[2 * i + 1] != 0) f = 1;
    if (f) flag = 1;   // benign race: all writers store 1
    __syncthreads();
    if (threadIdx.x == 0) *mode = flag;
}

// ---------------- coarse histogram: per-block LDS hist, NO global atomics ----------------
__global__ __launch_bounds__(256) void k_hist(const int* __restrict__ ei,
                                              const int* __restrict__ mode,
                                              int* __restrict__ gh, int E, int chunk) {
    __shared__ int hist[NBUK];
    int tid = threadIdx.x, k = blockIdx.x;
    for (int b = tid; b < NBUK; b += 256) hist[b] = 0;
    __syncthreads();
    int m = *mode;
    int e0 = k * chunk, e1 = min(E, e0 + chunk);
    for (int e = e0 + tid; e < e1; e += 256) {
        int d = m ? ei[E + e] : ei[2 * (E + e)];
        if ((unsigned)d >= N_NODES) d = 0;
        atomicAdd(&hist[d >> BSHIFT], 1);   // LDS atomic
    }
    __syncthreads();
    for (int b = tid; b < NBUK; b += 256) gh[k * NBUK + b] = hist[b];
}

// ---------------- per-bucket totals (391 blocks) ----------------
__global__ __launch_bounds__(256) void k_btot(const int* __restrict__ gh, int* __restrict__ btot) {
    __shared__ int s[256];
    int b = blockIdx.x, tid = threadIdx.x;
    s[tid] = gh[tid * NBUK + b];
    __syncthreads();
    for (int d = 128; d > 0; d >>= 1) {
        if (tid < d) s[tid] += s[tid + d];
        __syncthreads();
    }
    if (tid == 0) btot[b] = s[0];
}

// ---------------- scan of bucket totals -> bucket bases ----------------
__global__ void k_scan_btot(const int* __restrict__ btot, int* __restrict__ bbase,
                            int* __restrict__ rowptr, int E) {
    __shared__ int s[512];
    int tid = threadIdx.x;
    int v = (tid < NBUK) ? btot[tid] : 0;
    s[tid] = v;
    __syncthreads();
    for (int d = 1; d < 512; d <<= 1) {
        int t = (tid >= d) ? s[tid - d] : 0;
        __syncthreads();
        s[tid] += t;
        __syncthreads();
    }
    if (tid < NBUK) bbase[tid] = s[tid] - v;   // exclusive
    if (tid == 0) { bbase[NBUK] = E; rowptr[N_NODES] = E; }
}

// ---------------- per-bucket column scans: gh -> per-(block,bucket) write offsets (in place) ----
__global__ __launch_bounds__(256) void k_scan_cols(int* __restrict__ gh, const int* __restrict__ bbase) {
    __shared__ int s[256];
    int b = blockIdx.x, tid = threadIdx.x;
    int v = gh[tid * NBUK + b];
    s[tid] = v;
    __syncthreads();
    for (int d = 1; d < 256; d <<= 1) {
        int t = (tid >= d) ? s[tid - d] : 0;
        __syncthreads();
        s[tid] += t;
        __syncthreads();
    }
    gh[tid * NBUK + b] = bbase[b] + s[tid] - v;
}

// ---------------- bucketize: ranked scatter into coarse buckets, LDS cursors only ----------------
__global__ __launch_bounds__(256) void k_bucketize(const int* __restrict__ ei,
                                                   const int* __restrict__ mode,
                                                   const int* __restrict__ offs,
                                                   int2* __restrict__ bp, int E, int chunk) {
    __shared__ int cur[NBUK];
    int tid = threadIdx.x, k = blockIdx.x;
    for (int b = tid; b < NBUK; b += 256) cur[b] = offs[k * NBUK + b];
    __syncthreads();
    int m = *mode;
    int e0 = k * chunk, e1 = min(E, e0 + chunk);
    for (int e = e0 + tid; e < e1; e += 256) {
        int s, d;
        if (m) { s = ei[e]; d = ei[E + e]; }
        else   { s = ei[2 * e]; d = ei[2 * (E + e)]; }
        if ((unsigned)s >= N_NODES) s = 0;
        if ((unsigned)d >= N_NODES) d = 0;
        int pos = atomicAdd(&cur[d >> BSHIFT], 1);   // LDS atomic
        int2 p; p.x = s; p.y = d;
        bp[pos] = p;
    }
}

// ---------------- per-bucket CSR build: LDS counts/scan/cursors, writes rowptr+dinv+csr ----------
__global__ __launch_bounds__(256) void k_build_csr(const int2* __restrict__ bp,
                                                   const int* __restrict__ bbase,
                                                   int* __restrict__ rowptr,
                                                   float* __restrict__ dinv,
                                                   int* __restrict__ csr) {
    __shared__ int cnt[256];
    __shared__ int s[256];
    __shared__ int cur[256];
    int b = blockIdx.x, tid = threadIdx.x;
    int nb = b << BSHIFT;
    int estart = bbase[b], eend = bbase[b + 1];
    cnt[tid] = 0;
    __syncthreads();
    for (int e = estart + tid; e < eend; e += 256) {
        int2 p = bp[e];
        atomicAdd(&cnt[p.y - nb], 1);   // LDS atomic
    }
    __syncthreads();
    int v = cnt[tid];
    s[tid] = v;
    __syncthreads();
    for (int d = 1; d < 256; d <<= 1) {
        int t = (tid >= d) ? s[tid - d] : 0;
        __syncthreads();
        s[tid] += t;
        __syncthreads();
    }
    int excl = s[tid] - v;
    int node = nb + tid;
    if (node < N_NODES) {
        rowptr[node] = estart + excl;
        dinv[node] = rsqrtf((float)v + 1.0f);
    }
    cur[tid] = estart + excl;
    __syncthreads();
    for (int e = estart + tid; e < eend; e += 256) {
        int2 p = bp[e];
        int pos = atomicAdd(&cur[p.y - nb], 1);   // LDS atomic
        csr[pos] = p.x;
    }
}

// ---------------- GEMM1: H_pre[100000,32] = (X[100000,512] @ W[512,32]) * dinv, f32, split-K x4 ---
__global__ __launch_bounds__(256) void k_gemm1(const float* __restrict__ X,
                                               const float* __restrict__ W,
                                               const float* __restrict__ dinv,
                                               float* __restrict__ H) {
    __shared__ float lds[8448];
    float* xs  = lds;          // [64][65]
    float* wsw = lds + 4160;   // [64][32]
    int tid = threadIdx.x;
    int row = tid & 63;
    int kc  = tid >> 6;
    long row0 = (long)blockIdx.x * 64;

    float acc[32];
#pragma unroll
    for (int c = 0; c < 32; c++) acc[c] = 0.f;

    for (int k0 = 0; k0 < 512; k0 += 64) {
        __syncthreads();
#pragma unroll
        for (int u = 0; u < 8; u++) {
            int idx = u * 256 + tid;
            wsw[idx] = W[k0 * 32 + idx];
        }
#pragma unroll
        for (int u = 0; u < 4; u++) {
            int idx = u * 256 + tid;
            int rr = idx >> 4, j = idx & 15;
            long grow = row0 + rr;
            f32x4 v = {0.f, 0.f, 0.f, 0.f};
            if (grow < N_NODES) v = *(const f32x4*)&X[grow * 512 + k0 + 4 * j];
            float* dp = &xs[rr * 65 + 4 * j];
            dp[0] = v.x; dp[1] = v.y; dp[2] = v.z; dp[3] = v.w;
        }
        __syncthreads();
        int kbase = kc * 16;
#pragma unroll
        for (int kk = 0; kk < 16; kk++) {
            float xk = xs[row * 65 + kbase + kk];
            const float* wrow = &wsw[(kbase + kk) * 32];
#pragma unroll
            for (int c = 0; c < 32; c += 4) {
                f32x4 wv = *(const f32x4*)&wrow[c];
                acc[c]     += xk * wv.x;
                acc[c + 1] += xk * wv.y;
                acc[c + 2] += xk * wv.z;
                acc[c + 3] += xk * wv.w;
            }
        }
    }
    __syncthreads();
#pragma unroll
    for (int c = 0; c < 32; c++) lds[(kc * 64 + row) * 33 + c] = acc[c];
    __syncthreads();
#pragma unroll
    for (int i = 0; i < 8; i++) {
        int o = i * 256 + tid;
        int r = o >> 5, c = o & 31;
        float sv = lds[r * 33 + c] + lds[(64 + r) * 33 + c]
                 + lds[(128 + r) * 33 + c] + lds[(192 + r) * 33 + c];
        long grow = row0 + r;
        if (grow < N_NODES) H[grow * 32 + c] = sv * dinv[grow];
    }
}

// ---------------- shared gather core: asum = sum_{e} H_pre[csr[e]*32+f] ----------------
__device__ __forceinline__ float gather_sum(const float* __restrict__ Hf,
                                            const int* __restrict__ csr,
                                            int e0, int e1, int f) {
    float a0 = 0.f, a1 = 0.f, a2 = 0.f, a3 = 0.f;
    for (int base = e0; base < e1; base += 32) {
        int idx = base + f;
        int sl = (idx < e1) ? csr[idx] : 0;    // one coalesced 32-wide load
        int mm = e1 - base;
        if (mm >= 32) {
#pragma unroll
            for (int j = 0; j < 32; j += 4) {
                int s0 = __shfl(sl, j, 32);
                int s1 = __shfl(sl, j + 1, 32);
                int s2 = __shfl(sl, j + 2, 32);
                int s3 = __shfl(sl, j + 3, 32);
                a0 += Hf[(long)s0 * 32];
                a1 += Hf[(long)s1 * 32];
                a2 += Hf[(long)s2 * 32];
                a3 += Hf[(long)s3 * 32];
            }
        } else {
            for (int j = 0; j < mm; j++) {
                int s0 = __shfl(sl, j, 32);
                a0 += Hf[(long)s0 * 32];
            }
        }
    }
    return (a0 + a1) + (a2 + a3);
}

// ---------------- fused: x = relu(dv*(agg+self)+b); Hout_pre = (x @ W) * dv ----------------
__global__ __launch_bounds__(256) void k_agg_mm(const float* __restrict__ H,
                                                const int* __restrict__ rowptr,
                                                const int* __restrict__ csr,
                                                const float* __restrict__ dinv,
                                                const float* __restrict__ bias,
                                                const float* __restrict__ W,
                                                float* __restrict__ Hout, int n) {
    __shared__ float ws[1024];
    int tid = threadIdx.x;
    for (int t = tid; t < 1024; t += 256) ws[t] = W[t];
    __syncthreads();
    int node = blockIdx.x * 8 + (tid >> 5);
    int f = tid & 31;
    if (node >= n) return;
    int e0 = rowptr[node], e1 = rowptr[node + 1];
    const float* Hf = H + f;
    float asum = gather_sum(Hf, csr, e0, e1, f);
    float dv = dinv[node];
    float v = dv * (asum + Hf[(long)node * 32]) + bias[f];
    v = fmaxf(v, 0.f);
    float o = 0.f;
#pragma unroll
    for (int k = 0; k < 32; k++) {
        float vk = __shfl(v, k, 32);
        o += vk * ws[k * 32 + f];
    }
    Hout[(long)node * 32 + f] = o * dv;
}

// ---------------- fused: x3 = relu(dv*(agg+self)+b); out = relu(x3@lin1+b1)@lin2+b2 ----------------
__global__ __launch_bounds__(256) void k_agg_head(const float* __restrict__ H,
                                                  const int* __restrict__ rowptr,
                                                  const int* __restrict__ csr,
                                                  const float* __restrict__ dinv,
                                                  const float* __restrict__ bias,
                                                  const float* __restrict__ L1W,
                                                  const float* __restrict__ L1B,
                                                  const float* __restrict__ L2W,
                                                  const float* __restrict__ L2B,
                                                  float* __restrict__ out, int n) {
    __shared__ float w1[512];   // [32][16]
    __shared__ float w2[160];   // [16][10]
    __shared__ float bb1[16];
    __shared__ float bb2[10];
    int tid = threadIdx.x;
    for (int t = tid; t < 512; t += 256) w1[t] = L1W[t];
    if (tid < 160) w2[tid] = L2W[tid];
    if (tid < 16) bb1[tid] = L1B[tid];
    if (tid < 10) bb2[tid] = L2B[tid];
    __syncthreads();
    int node = blockIdx.x * 8 + (tid >> 5);
    int f = tid & 31;
    if (node >= n) return;
    int e0 = rowptr[node], e1 = rowptr[node + 1];
    const float* Hf = H + f;
    float asum = gather_sum(Hf, csr, e0, e1, f);
    float dv = dinv[node];
    float v = dv * (asum + Hf[(long)node * 32]) + bias[f];
    v = fmaxf(v, 0.f);
    int c1 = f & 15;
    float t1 = 0.f;
#pragma unroll
    for (int k = 0; k < 32; k++) {
        float vk = __shfl(v, k, 32);
        t1 += vk * w1[k * 16 + c1];
    }
    t1 = fmaxf(t1 + bb1[c1], 0.f);
    int c2 = (f < 10) ? f : 0;
    float o = 0.f;
#pragma unroll
    for (int k = 0; k < 16; k++) {
        float tk = __shfl(t1, k, 32);
        o += tk * w2[k * 10 + c2];
    }
    o += bb2[c2];
    if (f < 10) out[(long)node * 10 + f] = o;
}

extern "C" void kernel_launch(void* const* d_in, const int* in_sizes, int n_in,
                              void* d_out, int out_size, void* d_ws, size_t ws_size,
                              hipStream_t stream) {
    const float* x0 = (const float*)d_in[0];
    const int* ei = (const int*)d_in[1];
    const float* W1 = (const float*)d_in[3];
    const float* b1 = (const float*)d_in[4];
    const float* W2 = (const float*)d_in[5];
    const float* b2 = (const float*)d_in[6];
    const float* W3 = (const float*)d_in[7];
    const float* b3 = (const float*)d_in[8];
    const float* l1W = (const float*)d_in[9];
    const float* l1b = (const float*)d_in[10];
    const float* l2W = (const float*)d_in[11];
    const float* l2b = (const float*)d_in[12];

    const int E = in_sizes[1] / 2;
    const int N = N_NODES;

    char* w = (char*)d_ws;
    // bp (25.6 MB) aliases h+xb: dead before k_gemm1 writes h.
    float* h      = (float*)(w);                   // 12,800,000 B
    float* xb     = (float*)(w + 12800000);        // 12,800,000 B
    int2*  bp     = (int2*) (w);                   // 25,600,000 B (alias)
    int*   gh     = (int*)  (w + 25600000);        //    400,384 B  (HBLK*NBUK)
    int*   btot   = (int*)  (w + 26000384);        //      1,564 B
    int*   bbase  = (int*)  (w + 26001948);        //      1,568 B  (NBUK+1)
    int*   rowptr = (int*)  (w + 26003516);        //    400,016 B
    float* dinv   = (float*)(w + 26403532);        //    400,000 B
    int*   csr    = (int*)  (w + 26803532);        // 12,800,000 B
    int*   mode   = (int*)  (w + 39603532);        //          4 B

    const int chunk = (E + HBLK - 1) / HBLK;   // 12500
    const int AGB = (N + 7) / 8;               // 12500
    const int G1B = (N + 63) / 64;             // 1563

    // --- CSR build: zero global atomics ---
    k_detect<<<1, 256, 0, stream>>>(ei, mode);
    k_hist<<<HBLK, 256, 0, stream>>>(ei, mode, gh, E, chunk);
    k_btot<<<NBUK, 256, 0, stream>>>(gh, btot);
    k_scan_btot<<<1, 512, 0, stream>>>(btot, bbase, rowptr, E);
    k_scan_cols<<<NBUK, 256, 0, stream>>>(gh, bbase);
    k_bucketize<<<HBLK, 256, 0, stream>>>(ei, mode, gh, bp, E, chunk);
    k_build_csr<<<NBUK, 256, 0, stream>>>(bp, bbase, rowptr, dinv, csr);

    // --- layers (transform + head fused into aggregation epilogues; H pre-scaled by dinv) ---
    k_gemm1<<<G1B, 256, 0, stream>>>(x0, W1, dinv, h);
    k_agg_mm<<<AGB, 256, 0, stream>>>(h, rowptr, csr, dinv, b1, W2, xb, N);
    k_agg_mm<<<AGB, 256, 0, stream>>>(xb, rowptr, csr, dinv, b2, W3, h, N);
    k_agg_head<<<AGB, 256, 0, stream>>>(h, rowptr, csr, dinv, b3,
                                        l1W, l1b, l2W, l2b, (float*)d_out, N);
}